// Round 3
// baseline (732.696 us; speedup 1.0000x reference)
//
#include <hip/hip_runtime.h>
#include <cstdint>
#include <cstddef>

#define N_NODES 50000
#define N_EDGES 800000
#define N_ETOT  850000   // E + N self-loops
#define DIM     128
#define NHEAD   8
#define NGRAPH  100
#define NLAT    64
#define NSCAN   49       // ceil(50000/1024)
#define NEG_SLOPE 0.2f
#define BN_EPS  1e-5f

typedef unsigned int   u32;
typedef unsigned short u16;

__device__ __forceinline__ float b2f(u16 u){
    union { u32 i; float f; } v; v.i = ((u32)u) << 16; return v.f;
}
__device__ __forceinline__ u16 f2b(float f){
    union { float f; u32 i; } v; v.f = f;
    u32 u = v.i;
    u32 r = (u + 0x7fffu + ((u >> 16) & 1u)) >> 16;
    return (u16)r;
}

// ---------------- CSR build ----------------

__global__ void k_degree(const int* __restrict__ ei, int* __restrict__ deg){
    int e = blockIdx.x * blockDim.x + threadIdx.x;
    if (e < N_ETOT) {
        int d = (e < N_EDGES) ? ei[N_EDGES + e] : (e - N_EDGES);
        atomicAdd(&deg[d], 1);
    }
}

__global__ void k_bsum(const int* __restrict__ deg, int* __restrict__ bsum){
    __shared__ int s[256];
    int b = blockIdx.x, tid = threadIdx.x;
    int base = b * 1024 + tid * 4;
    int sum = 0;
    #pragma unroll
    for (int j = 0; j < 4; j++) { int n = base + j; if (n < N_NODES) sum += deg[n]; }
    s[tid] = sum; __syncthreads();
    for (int off = 128; off > 0; off >>= 1) {
        if (tid < off) s[tid] += s[tid + off];
        __syncthreads();
    }
    if (tid == 0) bsum[b] = s[0];
}

__global__ void k_scan_bsum(const int* __restrict__ bsum, int* __restrict__ boff,
                            int* __restrict__ rowptr){
    if (threadIdx.x == 0) {
        int acc = 0;
        for (int i = 0; i < NSCAN; i++) { boff[i] = acc; acc += bsum[i]; }
        rowptr[N_NODES] = acc;   // == N_ETOT
    }
}

__global__ void k_scan_local(const int* __restrict__ deg, const int* __restrict__ boff,
                             int* __restrict__ rowptr){
    __shared__ int s[256];
    int b = blockIdx.x, tid = threadIdx.x;
    int base = b * 1024 + tid * 4;
    int v[4];
    int sum = 0;
    #pragma unroll
    for (int j = 0; j < 4; j++) {
        int n = base + j;
        v[j] = (n < N_NODES) ? deg[n] : 0;
        sum += v[j];
    }
    s[tid] = sum; __syncthreads();
    for (int off = 1; off < 256; off <<= 1) {
        int t = (tid >= off) ? s[tid - off] : 0;
        __syncthreads();
        s[tid] += t;
        __syncthreads();
    }
    int ex = (tid ? s[tid - 1] : 0) + boff[b];
    #pragma unroll
    for (int j = 0; j < 4; j++) {
        int n = base + j;
        if (n < N_NODES) rowptr[n] = ex;
        ex += v[j];
    }
}

__global__ void k_initcur(const int* __restrict__ rowptr, int* __restrict__ cur){
    int n = blockIdx.x * blockDim.x + threadIdx.x;
    if (n < N_NODES) cur[n] = rowptr[n];
}

__global__ void k_scatter(const int* __restrict__ ei, int* __restrict__ cur,
                          int* __restrict__ csr){
    int e = blockIdx.x * blockDim.x + threadIdx.x;
    if (e < N_ETOT) {
        int s, d;
        if (e < N_EDGES) { s = ei[e]; d = ei[N_EDGES + e]; }
        else             { s = e - N_EDGES; d = s; }
        int pos = atomicAdd(&cur[d], 1);
        csr[pos] = s;
    }
}

// ---------------- per-layer: x @ W -> hp (bf16) + fused alpha logits ----------
// block: 256 thr, 64 rows/block. LDS: xs 32KB fp32.
// thread (cq=tid&31, rg=tid>>5): cols 4cq..4cq+3, rows rg*8..rg*8+7.
// Epilogue: alpha_src/dst dot-products in fp32 via 4-lane shfl reduction
// (head h = cq>>2 spans lanes 4h..4h+3 within the rg half-wave).

__launch_bounds__(256)
__global__ void k_gemm(const float* __restrict__ x, const float* __restrict__ W,
                       const float* __restrict__ asrc, const float* __restrict__ adst,
                       u16* __restrict__ hp,
                       float* __restrict__ as_, float* __restrict__ ad_){
    __shared__ float xs[64 * 128];
    const int tid = threadIdx.x;
    const int r0  = blockIdx.x * 64;

    for (int c = tid; c < 2048; c += 256) {          // 64 rows x 32 float4
        int row = r0 + (c >> 5);
        float4 v = make_float4(0.f, 0.f, 0.f, 0.f);
        if (row < N_NODES) v = *(const float4*)(x + (size_t)row * 128 + (c & 31) * 4);
        *(float4*)(xs + c * 4) = v;
    }
    __syncthreads();

    const int cq = tid & 31;
    const int rg = tid >> 5;
    float acc[8][4];
    #pragma unroll
    for (int r = 0; r < 8; r++)
        #pragma unroll
        for (int c = 0; c < 4; c++) acc[r][c] = 0.f;

    for (int k = 0; k < 128; k += 4) {
        float4 w0 = *(const float4*)(W + (k + 0) * 128 + 4 * cq);
        float4 w1 = *(const float4*)(W + (k + 1) * 128 + 4 * cq);
        float4 w2 = *(const float4*)(W + (k + 2) * 128 + 4 * cq);
        float4 w3 = *(const float4*)(W + (k + 3) * 128 + 4 * cq);
        #pragma unroll
        for (int rr = 0; rr < 8; rr++) {
            float4 xv = *(const float4*)(xs + (rg * 8 + rr) * 128 + k);
            acc[rr][0] = fmaf(xv.x, w0.x, acc[rr][0]);
            acc[rr][1] = fmaf(xv.x, w0.y, acc[rr][1]);
            acc[rr][2] = fmaf(xv.x, w0.z, acc[rr][2]);
            acc[rr][3] = fmaf(xv.x, w0.w, acc[rr][3]);
            acc[rr][0] = fmaf(xv.y, w1.x, acc[rr][0]);
            acc[rr][1] = fmaf(xv.y, w1.y, acc[rr][1]);
            acc[rr][2] = fmaf(xv.y, w1.z, acc[rr][2]);
            acc[rr][3] = fmaf(xv.y, w1.w, acc[rr][3]);
            acc[rr][0] = fmaf(xv.z, w2.x, acc[rr][0]);
            acc[rr][1] = fmaf(xv.z, w2.y, acc[rr][1]);
            acc[rr][2] = fmaf(xv.z, w2.z, acc[rr][2]);
            acc[rr][3] = fmaf(xv.z, w2.w, acc[rr][3]);
            acc[rr][0] = fmaf(xv.w, w3.x, acc[rr][0]);
            acc[rr][1] = fmaf(xv.w, w3.y, acc[rr][1]);
            acc[rr][2] = fmaf(xv.w, w3.z, acc[rr][2]);
            acc[rr][3] = fmaf(xv.w, w3.w, acc[rr][3]);
        }
    }

    const int h  = cq >> 2;
    const int c0 = (cq & 3) * 4;
    const float4 av = *(const float4*)(asrc + h * 16 + c0);
    const float4 bv = *(const float4*)(adst + h * 16 + c0);

    #pragma unroll
    for (int rr = 0; rr < 8; rr++) {
        int row = r0 + rg * 8 + rr;
        // bf16 pack/store
        if (row < N_NODES) {
            uint2 p;
            p.x = (u32)f2b(acc[rr][0]) | ((u32)f2b(acc[rr][1]) << 16);
            p.y = (u32)f2b(acc[rr][2]) | ((u32)f2b(acc[rr][3]) << 16);
            *(uint2*)(hp + (size_t)row * 128 + 4 * cq) = p;
        }
        // fp32 alpha logits: reduce 4 lanes of the same head
        float s0 = acc[rr][0] * av.x + acc[rr][1] * av.y + acc[rr][2] * av.z + acc[rr][3] * av.w;
        float s1 = acc[rr][0] * bv.x + acc[rr][1] * bv.y + acc[rr][2] * bv.z + acc[rr][3] * bv.w;
        s0 += __shfl_xor(s0, 1); s0 += __shfl_xor(s0, 2);
        s1 += __shfl_xor(s1, 1); s1 += __shfl_xor(s1, 2);
        if ((cq & 3) == 0 && row < N_NODES) {
            as_[(size_t)row * 8 + h] = s0;
            ad_[(size_t)row * 8 + h] = s1;
        }
    }
}

// ---------------- per-layer: segment softmax + aggregate + bias + ELU ----------
// one wave per destination node; 4 waves / 256-thr block.
// phase 3: lane owns cols 2*lane, 2*lane+1 (head = lane>>3); one u32 bf16-pair
// gather per lane per edge = 256 B/wave/edge.

__launch_bounds__(256)
__global__ void k_agg(const int* __restrict__ rowptr, const int* __restrict__ csr,
                      const float* __restrict__ as_, const float* __restrict__ ad_,
                      const u32* __restrict__ hp32, const float* __restrict__ bias,
                      float* __restrict__ xout){
    const int lane = threadIdx.x & 63;
    const int wid  = threadIdx.x >> 6;
    const int n    = blockIdx.x * 4 + wid;
    if (n >= N_NODES) return;
    const int beg = rowptr[n], end = rowptr[n + 1];
    const int items = (end - beg) * 8;
    const int hme = lane & 7;
    const float adn = ad_[(size_t)n * 8 + hme];

    // phase 1: per-head max of leaky_relu(as[src]+ad[n])
    float m = -1e30f;
    for (int j = lane; j < items; j += 64) {
        int s = csr[beg + (j >> 3)];
        float v = as_[(size_t)s * 8 + hme] + adn;
        v = v > 0.f ? v : NEG_SLOPE * v;
        m = fmaxf(m, v);
    }
    m = fmaxf(m, __shfl_xor(m, 8));
    m = fmaxf(m, __shfl_xor(m, 16));
    m = fmaxf(m, __shfl_xor(m, 32));

    // phase 2: per-head sum of exp(logit - m)
    float den = 0.f;
    for (int j = lane; j < items; j += 64) {
        int s = csr[beg + (j >> 3)];
        float v = as_[(size_t)s * 8 + hme] + adn;
        v = v > 0.f ? v : NEG_SLOPE * v;
        den += __expf(v - m);
    }
    den += __shfl_xor(den, 8);
    den += __shfl_xor(den, 16);
    den += __shfl_xor(den, 32);

    // phase 3: weighted aggregate
    const int h = lane >> 3;                    // head for cols 2*lane, 2*lane+1
    const float mh  = __shfl(m, h);
    const float ih  = 1.f / (__shfl(den, h) + 1e-16f);
    const float anh = __shfl(adn, h);
    float acc0 = 0.f, acc1 = 0.f;
    for (int e = beg; e < end; e++) {
        int s = csr[e];
        float v = as_[(size_t)s * 8 + h] + anh;
        v = v > 0.f ? v : NEG_SLOPE * v;
        float a = __expf(v - mh) * ih;
        u32 p = hp32[(size_t)s * 64 + lane];
        acc0 = fmaf(a, b2f((u16)(p & 0xffff)), acc0);
        acc1 = fmaf(a, b2f((u16)(p >> 16)),    acc1);
    }

    float o0 = acc0 + bias[2 * lane];
    float o1 = acc1 + bias[2 * lane + 1];
    o0 = o0 > 0.f ? o0 : (__expf(o0) - 1.f);   // ELU
    o1 = o1 > 0.f ? o1 : (__expf(o1) - 1.f);
    *(float2*)(xout + (size_t)n * 128 + 2 * lane) = make_float2(o0, o1);
}

// ---------------- pooling / BN+FC ----------------

#define POOL_CHUNK 50

__global__ void k_pool(const float* __restrict__ x, const int* __restrict__ batch,
                       float* __restrict__ pooled){
    int tid = threadIdx.x;             // 128 = feature
    int n0 = blockIdx.x * POOL_CHUNK;
    int nend = min(n0 + POOL_CHUNK, N_NODES);
    float acc = 0.f;
    int cur = batch[n0];
    for (int n = n0; n < nend; n++) {
        int g = batch[n];
        if (g != cur) {
            atomicAdd(&pooled[cur * 128 + tid], acc);
            acc = 0.f; cur = g;
        }
        acc += x[(size_t)n * 128 + tid];
    }
    atomicAdd(&pooled[cur * 128 + tid], acc);
}

__launch_bounds__(256)
__global__ void k_bnfc(const float* __restrict__ pooled, const float* __restrict__ gamma,
                       const float* __restrict__ beta, const float* __restrict__ fw,
                       const float* __restrict__ fb, float* __restrict__ out){
    __shared__ float sn[NGRAPH * 128];   // 51.2 KB
    int tid = threadIdx.x;
    if (tid < 128) {
        int f = tid;
        float mu = 0.f;
        for (int g = 0; g < NGRAPH; g++) mu += pooled[g * 128 + f];
        mu *= (1.f / NGRAPH);
        float var = 0.f;
        for (int g = 0; g < NGRAPH; g++) { float d = pooled[g * 128 + f] - mu; var += d * d; }
        var *= (1.f / NGRAPH);
        float rs = rsqrtf(var + BN_EPS);
        float ga = gamma[f], be = beta[f];
        for (int g = 0; g < NGRAPH; g++)
            sn[g * 128 + f] = (pooled[g * 128 + f] - mu) * rs * ga + be;
    }
    __syncthreads();
    for (int o = tid; o < NGRAPH * NLAT; o += 256) {
        int g = o >> 6, j = o & 63;
        float acc = fb[j];
        const float* wr = fw + j * 128;
        const float* nr = sn + g * 128;
        #pragma unroll 16
        for (int k = 0; k < 128; k++)
            acc = fmaf(nr[k], wr[k], acc);
        out[o] = acc;
    }
}

// ---------------- launch ----------------

extern "C" void kernel_launch(void* const* d_in, const int* in_sizes, int n_in,
                              void* d_out, int out_size, void* d_ws, size_t ws_size,
                              hipStream_t stream) {
    const float* x0    = (const float*)d_in[0];
    const int*   ei    = (const int*)d_in[1];
    const int*   batch = (const int*)d_in[2];
    const float* Wp    = (const float*)d_in[3];
    const float* asrc  = (const float*)d_in[4];
    const float* adst  = (const float*)d_in[5];
    const float* bias  = (const float*)d_in[6];
    const float* gamma = (const float*)d_in[7];
    const float* beta  = (const float*)d_in[8];
    const float* fw    = (const float*)d_in[9];
    const float* fb    = (const float*)d_in[10];
    float* out = (float*)d_out;

    char* w = (char*)d_ws;
    size_t off = 0;
    auto take = [&](size_t bytes) -> char* {
        char* p = w + off;
        off += (bytes + 255) & ~(size_t)255;
        return p;
    };
    int*   rowptr = (int*)take((N_NODES + 1) * 4);
    int*   cur    = (int*)take((size_t)N_NODES * 4);      // also the degree histogram
    int*   bsum   = (int*)take(64 * 4);
    int*   boff   = (int*)take(64 * 4);
    int*   csr    = (int*)take((size_t)N_ETOT * 4);
    u16*   hp     = (u16*)take((size_t)N_NODES * 128 * 2);
    float* as_    = (float*)take((size_t)N_NODES * 8 * 4);
    float* ad_    = (float*)take((size_t)N_NODES * 8 * 4);
    float* xb1    = (float*)take((size_t)N_NODES * 128 * 4);
    float* xb2    = (float*)take((size_t)N_NODES * 128 * 4);
    float* pooled = (float*)take((size_t)NGRAPH * 128 * 4);

    hipMemsetAsync(cur, 0, (size_t)N_NODES * 4, stream);
    hipMemsetAsync(pooled, 0, (size_t)NGRAPH * 128 * 4, stream);

    // CSR build (by destination)
    k_degree   <<<(N_ETOT + 255) / 256, 256, 0, stream>>>(ei, cur);
    k_bsum     <<<NSCAN, 256, 0, stream>>>(cur, bsum);
    k_scan_bsum<<<1, 64, 0, stream>>>(bsum, boff, rowptr);
    k_scan_local<<<NSCAN, 256, 0, stream>>>(cur, boff, rowptr);
    k_initcur  <<<(N_NODES + 255) / 256, 256, 0, stream>>>(rowptr, cur);
    k_scatter  <<<(N_ETOT + 255) / 256, 256, 0, stream>>>(ei, cur, csr);

    // 3 GAT layers
    const float* xc = x0;
    float* bufs[2] = { xb1, xb2 };
    for (int l = 0; l < 3; l++) {
        float* xn = bufs[l & 1];
        k_gemm<<<(N_NODES + 63) / 64, 256, 0, stream>>>(
            xc, Wp + (size_t)l * 128 * 128, asrc + l * 128, adst + l * 128, hp, as_, ad_);
        k_agg <<<(N_NODES + 3) / 4, 256, 0, stream>>>(
            rowptr, csr, as_, ad_, (const u32*)hp, bias + l * 128, xn);
        xc = xn;
    }

    // pool -> BN+FC
    k_pool<<<(N_NODES + POOL_CHUNK - 1) / POOL_CHUNK, 128, 0, stream>>>(xc, batch, pooled);
    k_bnfc<<<1, 256, 0, stream>>>(pooled, gamma, beta, fw, fb, out);
}

// Round 4
// 551.698 us; speedup vs baseline: 1.3281x; 1.3281x over previous
//
#include <hip/hip_runtime.h>
#include <cstdint>
#include <cstddef>

#define N_NODES 50000
#define N_EDGES 800000
#define N_ETOT  850000   // E + N self-loops
#define DIM     128
#define NHEAD   8
#define NGRAPH  100
#define NLAT    64
#define NSCAN   49       // ceil(50000/1024)
#define NEG_SLOPE 0.2f
#define BN_EPS  1e-5f

typedef unsigned int   u32;
typedef unsigned short u16;

__device__ __forceinline__ float b2f(u16 u){
    union { u32 i; float f; } v; v.i = ((u32)u) << 16; return v.f;
}
__device__ __forceinline__ u16 f2b(float f){
    union { float f; u32 i; } v; v.f = f;
    u32 u = v.i;
    u32 r = (u + 0x7fffu + ((u >> 16) & 1u)) >> 16;
    return (u16)r;
}

// ---------------- CSR build ----------------

__global__ void k_degree(const int* __restrict__ ei, int* __restrict__ deg){
    int e = blockIdx.x * blockDim.x + threadIdx.x;
    if (e < N_ETOT) {
        int d = (e < N_EDGES) ? ei[N_EDGES + e] : (e - N_EDGES);
        atomicAdd(&deg[d], 1);
    }
}

__global__ void k_bsum(const int* __restrict__ deg, int* __restrict__ bsum){
    __shared__ int s[256];
    int b = blockIdx.x, tid = threadIdx.x;
    int base = b * 1024 + tid * 4;
    int sum = 0;
    #pragma unroll
    for (int j = 0; j < 4; j++) { int n = base + j; if (n < N_NODES) sum += deg[n]; }
    s[tid] = sum; __syncthreads();
    for (int off = 128; off > 0; off >>= 1) {
        if (tid < off) s[tid] += s[tid + off];
        __syncthreads();
    }
    if (tid == 0) bsum[b] = s[0];
}

__global__ void k_scan_bsum(const int* __restrict__ bsum, int* __restrict__ boff,
                            int* __restrict__ rowptr){
    if (threadIdx.x == 0) {
        int acc = 0;
        for (int i = 0; i < NSCAN; i++) { boff[i] = acc; acc += bsum[i]; }
        rowptr[N_NODES] = acc;   // == N_ETOT
    }
}

__global__ void k_scan_local(const int* __restrict__ deg, const int* __restrict__ boff,
                             int* __restrict__ rowptr){
    __shared__ int s[256];
    int b = blockIdx.x, tid = threadIdx.x;
    int base = b * 1024 + tid * 4;
    int v[4];
    int sum = 0;
    #pragma unroll
    for (int j = 0; j < 4; j++) {
        int n = base + j;
        v[j] = (n < N_NODES) ? deg[n] : 0;
        sum += v[j];
    }
    s[tid] = sum; __syncthreads();
    for (int off = 1; off < 256; off <<= 1) {
        int t = (tid >= off) ? s[tid - off] : 0;
        __syncthreads();
        s[tid] += t;
        __syncthreads();
    }
    int ex = (tid ? s[tid - 1] : 0) + boff[b];
    #pragma unroll
    for (int j = 0; j < 4; j++) {
        int n = base + j;
        if (n < N_NODES) rowptr[n] = ex;
        ex += v[j];
    }
}

__global__ void k_initcur(const int* __restrict__ rowptr, int* __restrict__ cur){
    int n = blockIdx.x * blockDim.x + threadIdx.x;
    if (n < N_NODES) cur[n] = rowptr[n];
}

__global__ void k_scatter(const int* __restrict__ ei, int* __restrict__ cur,
                          int* __restrict__ csr){
    int e = blockIdx.x * blockDim.x + threadIdx.x;
    if (e < N_ETOT) {
        int s, d;
        if (e < N_EDGES) { s = ei[e]; d = ei[N_EDGES + e]; }
        else             { s = e - N_EDGES; d = s; }
        int pos = atomicAdd(&cur[d], 1);
        csr[pos] = s;
    }
}

// ---------------- per-layer: x @ W -> hp (bf16) + fused alpha logits ----------

__launch_bounds__(256)
__global__ void k_gemm(const float* __restrict__ x, const float* __restrict__ W,
                       const float* __restrict__ asrc, const float* __restrict__ adst,
                       u16* __restrict__ hp,
                       float* __restrict__ as_, float* __restrict__ ad_){
    __shared__ float xs[64 * 128];
    const int tid = threadIdx.x;
    const int r0  = blockIdx.x * 64;

    for (int c = tid; c < 2048; c += 256) {          // 64 rows x 32 float4
        int row = r0 + (c >> 5);
        float4 v = make_float4(0.f, 0.f, 0.f, 0.f);
        if (row < N_NODES) v = *(const float4*)(x + (size_t)row * 128 + (c & 31) * 4);
        *(float4*)(xs + c * 4) = v;
    }
    __syncthreads();

    const int cq = tid & 31;
    const int rg = tid >> 5;
    float acc[8][4];
    #pragma unroll
    for (int r = 0; r < 8; r++)
        #pragma unroll
        for (int c = 0; c < 4; c++) acc[r][c] = 0.f;

    for (int k = 0; k < 128; k += 4) {
        float4 w0 = *(const float4*)(W + (k + 0) * 128 + 4 * cq);
        float4 w1 = *(const float4*)(W + (k + 1) * 128 + 4 * cq);
        float4 w2 = *(const float4*)(W + (k + 2) * 128 + 4 * cq);
        float4 w3 = *(const float4*)(W + (k + 3) * 128 + 4 * cq);
        #pragma unroll
        for (int rr = 0; rr < 8; rr++) {
            float4 xv = *(const float4*)(xs + (rg * 8 + rr) * 128 + k);
            acc[rr][0] = fmaf(xv.x, w0.x, acc[rr][0]);
            acc[rr][1] = fmaf(xv.x, w0.y, acc[rr][1]);
            acc[rr][2] = fmaf(xv.x, w0.z, acc[rr][2]);
            acc[rr][3] = fmaf(xv.x, w0.w, acc[rr][3]);
            acc[rr][0] = fmaf(xv.y, w1.x, acc[rr][0]);
            acc[rr][1] = fmaf(xv.y, w1.y, acc[rr][1]);
            acc[rr][2] = fmaf(xv.y, w1.z, acc[rr][2]);
            acc[rr][3] = fmaf(xv.y, w1.w, acc[rr][3]);
            acc[rr][0] = fmaf(xv.z, w2.x, acc[rr][0]);
            acc[rr][1] = fmaf(xv.z, w2.y, acc[rr][1]);
            acc[rr][2] = fmaf(xv.z, w2.z, acc[rr][2]);
            acc[rr][3] = fmaf(xv.z, w2.w, acc[rr][3]);
            acc[rr][0] = fmaf(xv.w, w3.x, acc[rr][0]);
            acc[rr][1] = fmaf(xv.w, w3.y, acc[rr][1]);
            acc[rr][2] = fmaf(xv.w, w3.z, acc[rr][2]);
            acc[rr][3] = fmaf(xv.w, w3.w, acc[rr][3]);
        }
    }

    const int h  = cq >> 2;
    const int c0 = (cq & 3) * 4;
    const float4 av = *(const float4*)(asrc + h * 16 + c0);
    const float4 bv = *(const float4*)(adst + h * 16 + c0);

    #pragma unroll
    for (int rr = 0; rr < 8; rr++) {
        int row = r0 + rg * 8 + rr;
        if (row < N_NODES) {
            uint2 p;
            p.x = (u32)f2b(acc[rr][0]) | ((u32)f2b(acc[rr][1]) << 16);
            p.y = (u32)f2b(acc[rr][2]) | ((u32)f2b(acc[rr][3]) << 16);
            *(uint2*)(hp + (size_t)row * 128 + 4 * cq) = p;
        }
        float s0 = acc[rr][0] * av.x + acc[rr][1] * av.y + acc[rr][2] * av.z + acc[rr][3] * av.w;
        float s1 = acc[rr][0] * bv.x + acc[rr][1] * bv.y + acc[rr][2] * bv.z + acc[rr][3] * bv.w;
        s0 += __shfl_xor(s0, 1); s0 += __shfl_xor(s0, 2);
        s1 += __shfl_xor(s1, 1); s1 += __shfl_xor(s1, 2);
        if ((cq & 3) == 0 && row < N_NODES) {
            as_[(size_t)row * 8 + h] = s0;
            ad_[(size_t)row * 8 + h] = s1;
        }
    }
}

// ---------------- per-layer: single-pass segment softmax + aggregate ----------
// One wave per destination node. Unnormalized-exp trick (logits are O(1),
// no overflow): acc_c += exp(v)*hp[s][c], den_h += exp(v); normalize at end.
// Gather layout: 16 lanes per hp row (uint4 = 16B/lane), 4 edges in flight
// per iteration. q = lane>>4 picks the edge slot; li = lane&15 picks cols
// 8*li..8*li+7 (head = li>>1).

__launch_bounds__(256)
__global__ void k_agg(const int* __restrict__ rowptr, const int* __restrict__ csr,
                      const float* __restrict__ as_, const float* __restrict__ ad_,
                      const uint4* __restrict__ hp4, const float* __restrict__ bias,
                      float* __restrict__ xout){
    const int lane = threadIdx.x & 63;
    const int wid  = threadIdx.x >> 6;
    const int n    = blockIdx.x * 4 + wid;
    if (n >= N_NODES) return;
    const int beg = rowptr[n], end = rowptr[n + 1];

    const int q  = lane >> 4;       // edge slot 0..3
    const int li = lane & 15;       // row position: cols 8*li .. 8*li+7
    const int h  = li >> 1;         // head
    const float adn = ad_[(size_t)n * 8 + h];

    float acc[8];
    #pragma unroll
    for (int j = 0; j < 8; j++) acc[j] = 0.f;
    float den = 0.f;

    for (int e0 = beg; e0 < end; e0 += 4) {
        int e = e0 + q;
        bool valid = (e < end);
        int ec = valid ? e : (end - 1);
        int s = csr[ec];
        float v = as_[(size_t)s * 8 + h] + adn;
        v = v > 0.f ? v : NEG_SLOPE * v;
        float w = valid ? __expf(v) : 0.f;
        den += w;
        uint4 p = hp4[(size_t)s * 16 + li];
        acc[0] = fmaf(w, b2f((u16)(p.x & 0xffff)), acc[0]);
        acc[1] = fmaf(w, b2f((u16)(p.x >> 16)),    acc[1]);
        acc[2] = fmaf(w, b2f((u16)(p.y & 0xffff)), acc[2]);
        acc[3] = fmaf(w, b2f((u16)(p.y >> 16)),    acc[3]);
        acc[4] = fmaf(w, b2f((u16)(p.z & 0xffff)), acc[4]);
        acc[5] = fmaf(w, b2f((u16)(p.z >> 16)),    acc[5]);
        acc[6] = fmaf(w, b2f((u16)(p.w & 0xffff)), acc[6]);
        acc[7] = fmaf(w, b2f((u16)(p.w >> 16)),    acc[7]);
    }

    // combine the 4 edge slots (butterfly over lanes 16, 32 apart)
    #pragma unroll
    for (int j = 0; j < 8; j++) {
        acc[j] += __shfl_xor(acc[j], 16);
        acc[j] += __shfl_xor(acc[j], 32);
    }
    den += __shfl_xor(den, 16);
    den += __shfl_xor(den, 32);

    if (q == 0) {
        const float inv = 1.f / (den + 1e-16f);
        const float4 b0 = *(const float4*)(bias + 8 * li);
        const float4 b1 = *(const float4*)(bias + 8 * li + 4);
        float o[8];
        o[0] = acc[0] * inv + b0.x; o[1] = acc[1] * inv + b0.y;
        o[2] = acc[2] * inv + b0.z; o[3] = acc[3] * inv + b0.w;
        o[4] = acc[4] * inv + b1.x; o[5] = acc[5] * inv + b1.y;
        o[6] = acc[6] * inv + b1.z; o[7] = acc[7] * inv + b1.w;
        #pragma unroll
        for (int j = 0; j < 8; j++)
            o[j] = o[j] > 0.f ? o[j] : (__expf(o[j]) - 1.f);   // ELU
        float* dst = xout + (size_t)n * 128 + 8 * li;
        *(float4*)(dst)     = make_float4(o[0], o[1], o[2], o[3]);
        *(float4*)(dst + 4) = make_float4(o[4], o[5], o[6], o[7]);
    }
}

// ---------------- pooling / BN+FC ----------------

#define POOL_CHUNK 50

__global__ void k_pool(const float* __restrict__ x, const int* __restrict__ batch,
                       float* __restrict__ pooled){
    int tid = threadIdx.x;             // 128 = feature
    int n0 = blockIdx.x * POOL_CHUNK;
    int nend = min(n0 + POOL_CHUNK, N_NODES);
    float acc = 0.f;
    int cur = batch[n0];
    for (int n = n0; n < nend; n++) {
        int g = batch[n];
        if (g != cur) {
            atomicAdd(&pooled[cur * 128 + tid], acc);
            acc = 0.f; cur = g;
        }
        acc += x[(size_t)n * 128 + tid];
    }
    atomicAdd(&pooled[cur * 128 + tid], acc);
}

__launch_bounds__(256)
__global__ void k_bnfc(const float* __restrict__ pooled, const float* __restrict__ gamma,
                       const float* __restrict__ beta, const float* __restrict__ fw,
                       const float* __restrict__ fb, float* __restrict__ out){
    __shared__ float sn[NGRAPH * 128];   // 51.2 KB
    int tid = threadIdx.x;
    if (tid < 128) {
        int f = tid;
        float mu = 0.f;
        for (int g = 0; g < NGRAPH; g++) mu += pooled[g * 128 + f];
        mu *= (1.f / NGRAPH);
        float var = 0.f;
        for (int g = 0; g < NGRAPH; g++) { float d = pooled[g * 128 + f] - mu; var += d * d; }
        var *= (1.f / NGRAPH);
        float rs = rsqrtf(var + BN_EPS);
        float ga = gamma[f], be = beta[f];
        for (int g = 0; g < NGRAPH; g++)
            sn[g * 128 + f] = (pooled[g * 128 + f] - mu) * rs * ga + be;
    }
    __syncthreads();
    for (int o = tid; o < NGRAPH * NLAT; o += 256) {
        int g = o >> 6, j = o & 63;
        float acc = fb[j];
        const float* wr = fw + j * 128;
        const float* nr = sn + g * 128;
        #pragma unroll 16
        for (int k = 0; k < 128; k++)
            acc = fmaf(nr[k], wr[k], acc);
        out[o] = acc;
    }
}

// ---------------- launch ----------------

extern "C" void kernel_launch(void* const* d_in, const int* in_sizes, int n_in,
                              void* d_out, int out_size, void* d_ws, size_t ws_size,
                              hipStream_t stream) {
    const float* x0    = (const float*)d_in[0];
    const int*   ei    = (const int*)d_in[1];
    const int*   batch = (const int*)d_in[2];
    const float* Wp    = (const float*)d_in[3];
    const float* asrc  = (const float*)d_in[4];
    const float* adst  = (const float*)d_in[5];
    const float* bias  = (const float*)d_in[6];
    const float* gamma = (const float*)d_in[7];
    const float* beta  = (const float*)d_in[8];
    const float* fw    = (const float*)d_in[9];
    const float* fb    = (const float*)d_in[10];
    float* out = (float*)d_out;

    char* w = (char*)d_ws;
    size_t off = 0;
    auto take = [&](size_t bytes) -> char* {
        char* p = w + off;
        off += (bytes + 255) & ~(size_t)255;
        return p;
    };
    int*   rowptr = (int*)take((N_NODES + 1) * 4);
    int*   cur    = (int*)take((size_t)N_NODES * 4);      // also the degree histogram
    int*   bsum   = (int*)take(64 * 4);
    int*   boff   = (int*)take(64 * 4);
    int*   csr    = (int*)take((size_t)N_ETOT * 4);
    u16*   hp     = (u16*)take((size_t)N_NODES * 128 * 2);
    float* as_    = (float*)take((size_t)N_NODES * 8 * 4);
    float* ad_    = (float*)take((size_t)N_NODES * 8 * 4);
    float* xb1    = (float*)take((size_t)N_NODES * 128 * 4);
    float* xb2    = (float*)take((size_t)N_NODES * 128 * 4);
    float* pooled = (float*)take((size_t)NGRAPH * 128 * 4);

    hipMemsetAsync(cur, 0, (size_t)N_NODES * 4, stream);
    hipMemsetAsync(pooled, 0, (size_t)NGRAPH * 128 * 4, stream);

    // CSR build (by destination)
    k_degree   <<<(N_ETOT + 255) / 256, 256, 0, stream>>>(ei, cur);
    k_bsum     <<<NSCAN, 256, 0, stream>>>(cur, bsum);
    k_scan_bsum<<<1, 64, 0, stream>>>(bsum, boff, rowptr);
    k_scan_local<<<NSCAN, 256, 0, stream>>>(cur, boff, rowptr);
    k_initcur  <<<(N_NODES + 255) / 256, 256, 0, stream>>>(rowptr, cur);
    k_scatter  <<<(N_ETOT + 255) / 256, 256, 0, stream>>>(ei, cur, csr);

    // 3 GAT layers
    const float* xc = x0;
    float* bufs[2] = { xb1, xb2 };
    for (int l = 0; l < 3; l++) {
        float* xn = bufs[l & 1];
        k_gemm<<<(N_NODES + 63) / 64, 256, 0, stream>>>(
            xc, Wp + (size_t)l * 128 * 128, asrc + l * 128, adst + l * 128, hp, as_, ad_);
        k_agg <<<(N_NODES + 3) / 4, 256, 0, stream>>>(
            rowptr, csr, as_, ad_, (const uint4*)hp, bias + l * 128, xn);
        xc = xn;
    }

    // pool -> BN+FC
    k_pool<<<(N_NODES + POOL_CHUNK - 1) / POOL_CHUNK, 128, 0, stream>>>(xc, batch, pooled);
    k_bnfc<<<1, 256, 0, stream>>>(pooled, gamma, beta, fw, fb, out);
}

// Round 5
// 458.594 us; speedup vs baseline: 1.5977x; 1.2030x over previous
//
#include <hip/hip_runtime.h>
#include <cstdint>
#include <cstddef>

#define N_NODES 50000
#define N_EDGES 800000
#define N_ETOT  850000   // E + N self-loops
#define DIM     128
#define NHEAD   8
#define NGRAPH  100
#define NLAT    64
#define NSCAN   49       // ceil(50000/1024)
#define NEG_SLOPE 0.2f
#define BN_EPS  1e-5f

typedef unsigned int   u32;
typedef unsigned short u16;

__device__ __forceinline__ float b2f(u16 u){
    union { u32 i; float f; } v; v.i = ((u32)u) << 16; return v.f;
}
__device__ __forceinline__ u16 f2b(float f){
    union { float f; u32 i; } v; v.f = f;
    u32 u = v.i;
    u32 r = (u + 0x7fffu + ((u >> 16) & 1u)) >> 16;
    return (u16)r;
}

// ---------------- CSR build ----------------

__global__ void k_degree(const int* __restrict__ ei, int* __restrict__ deg){
    int e = blockIdx.x * blockDim.x + threadIdx.x;
    if (e < N_ETOT) {
        int d = (e < N_EDGES) ? ei[N_EDGES + e] : (e - N_EDGES);
        atomicAdd(&deg[d], 1);
    }
}

__global__ void k_bsum(const int* __restrict__ deg, int* __restrict__ bsum){
    __shared__ int s[256];
    int b = blockIdx.x, tid = threadIdx.x;
    int base = b * 1024 + tid * 4;
    int sum = 0;
    #pragma unroll
    for (int j = 0; j < 4; j++) { int n = base + j; if (n < N_NODES) sum += deg[n]; }
    s[tid] = sum; __syncthreads();
    for (int off = 128; off > 0; off >>= 1) {
        if (tid < off) s[tid] += s[tid + off];
        __syncthreads();
    }
    if (tid == 0) bsum[b] = s[0];
}

__global__ void k_scan_bsum(const int* __restrict__ bsum, int* __restrict__ boff,
                            int* __restrict__ rowptr){
    if (threadIdx.x == 0) {
        int acc = 0;
        for (int i = 0; i < NSCAN; i++) { boff[i] = acc; acc += bsum[i]; }
        rowptr[N_NODES] = acc;   // == N_ETOT
    }
}

__global__ void k_scan_local(const int* __restrict__ deg, const int* __restrict__ boff,
                             int* __restrict__ rowptr){
    __shared__ int s[256];
    int b = blockIdx.x, tid = threadIdx.x;
    int base = b * 1024 + tid * 4;
    int v[4];
    int sum = 0;
    #pragma unroll
    for (int j = 0; j < 4; j++) {
        int n = base + j;
        v[j] = (n < N_NODES) ? deg[n] : 0;
        sum += v[j];
    }
    s[tid] = sum; __syncthreads();
    for (int off = 1; off < 256; off <<= 1) {
        int t = (tid >= off) ? s[tid - off] : 0;
        __syncthreads();
        s[tid] += t;
        __syncthreads();
    }
    int ex = (tid ? s[tid - 1] : 0) + boff[b];
    #pragma unroll
    for (int j = 0; j < 4; j++) {
        int n = base + j;
        if (n < N_NODES) rowptr[n] = ex;
        ex += v[j];
    }
}

__global__ void k_initcur(const int* __restrict__ rowptr, int* __restrict__ cur){
    int n = blockIdx.x * blockDim.x + threadIdx.x;
    if (n < N_NODES) cur[n] = rowptr[n];
}

__global__ void k_scatter(const int* __restrict__ ei, int* __restrict__ cur,
                          int* __restrict__ csr){
    int e = blockIdx.x * blockDim.x + threadIdx.x;
    if (e < N_ETOT) {
        int s, d;
        if (e < N_EDGES) { s = ei[e]; d = ei[N_EDGES + e]; }
        else             { s = e - N_EDGES; d = s; }
        int pos = atomicAdd(&cur[d], 1);
        csr[pos] = s;
    }
}

// ---------------- per-layer: x @ W -> hp (bf16) + fused alpha logits ----------

__launch_bounds__(256)
__global__ void k_gemm(const float* __restrict__ x, const float* __restrict__ W,
                       const float* __restrict__ asrc, const float* __restrict__ adst,
                       u16* __restrict__ hp,
                       float* __restrict__ as_, float* __restrict__ ad_){
    __shared__ float xs[64 * 128];
    const int tid = threadIdx.x;
    const int r0  = blockIdx.x * 64;

    for (int c = tid; c < 2048; c += 256) {          // 64 rows x 32 float4
        int row = r0 + (c >> 5);
        float4 v = make_float4(0.f, 0.f, 0.f, 0.f);
        if (row < N_NODES) v = *(const float4*)(x + (size_t)row * 128 + (c & 31) * 4);
        *(float4*)(xs + c * 4) = v;
    }
    __syncthreads();

    const int cq = tid & 31;
    const int rg = tid >> 5;
    float acc[8][4];
    #pragma unroll
    for (int r = 0; r < 8; r++)
        #pragma unroll
        for (int c = 0; c < 4; c++) acc[r][c] = 0.f;

    for (int k = 0; k < 128; k += 4) {
        float4 w0 = *(const float4*)(W + (k + 0) * 128 + 4 * cq);
        float4 w1 = *(const float4*)(W + (k + 1) * 128 + 4 * cq);
        float4 w2 = *(const float4*)(W + (k + 2) * 128 + 4 * cq);
        float4 w3 = *(const float4*)(W + (k + 3) * 128 + 4 * cq);
        #pragma unroll
        for (int rr = 0; rr < 8; rr++) {
            float4 xv = *(const float4*)(xs + (rg * 8 + rr) * 128 + k);
            acc[rr][0] = fmaf(xv.x, w0.x, acc[rr][0]);
            acc[rr][1] = fmaf(xv.x, w0.y, acc[rr][1]);
            acc[rr][2] = fmaf(xv.x, w0.z, acc[rr][2]);
            acc[rr][3] = fmaf(xv.x, w0.w, acc[rr][3]);
            acc[rr][0] = fmaf(xv.y, w1.x, acc[rr][0]);
            acc[rr][1] = fmaf(xv.y, w1.y, acc[rr][1]);
            acc[rr][2] = fmaf(xv.y, w1.z, acc[rr][2]);
            acc[rr][3] = fmaf(xv.y, w1.w, acc[rr][3]);
            acc[rr][0] = fmaf(xv.z, w2.x, acc[rr][0]);
            acc[rr][1] = fmaf(xv.z, w2.y, acc[rr][1]);
            acc[rr][2] = fmaf(xv.z, w2.z, acc[rr][2]);
            acc[rr][3] = fmaf(xv.z, w2.w, acc[rr][3]);
            acc[rr][0] = fmaf(xv.w, w3.x, acc[rr][0]);
            acc[rr][1] = fmaf(xv.w, w3.y, acc[rr][1]);
            acc[rr][2] = fmaf(xv.w, w3.z, acc[rr][2]);
            acc[rr][3] = fmaf(xv.w, w3.w, acc[rr][3]);
        }
    }

    const int h  = cq >> 2;
    const int c0 = (cq & 3) * 4;
    const float4 av = *(const float4*)(asrc + h * 16 + c0);
    const float4 bv = *(const float4*)(adst + h * 16 + c0);

    #pragma unroll
    for (int rr = 0; rr < 8; rr++) {
        int row = r0 + rg * 8 + rr;
        if (row < N_NODES) {
            uint2 p;
            p.x = (u32)f2b(acc[rr][0]) | ((u32)f2b(acc[rr][1]) << 16);
            p.y = (u32)f2b(acc[rr][2]) | ((u32)f2b(acc[rr][3]) << 16);
            *(uint2*)(hp + (size_t)row * 128 + 4 * cq) = p;
        }
        float s0 = acc[rr][0] * av.x + acc[rr][1] * av.y + acc[rr][2] * av.z + acc[rr][3] * av.w;
        float s1 = acc[rr][0] * bv.x + acc[rr][1] * bv.y + acc[rr][2] * bv.z + acc[rr][3] * bv.w;
        s0 += __shfl_xor(s0, 1); s0 += __shfl_xor(s0, 2);
        s1 += __shfl_xor(s1, 1); s1 += __shfl_xor(s1, 2);
        if ((cq & 3) == 0 && row < N_NODES) {
            as_[(size_t)row * 8 + h] = s0;
            ad_[(size_t)row * 8 + h] = s1;
        }
    }
}

// ---------------- per-layer: single-pass segment softmax + aggregate ----------

__launch_bounds__(256)
__global__ void k_agg(const int* __restrict__ rowptr, const int* __restrict__ csr,
                      const float* __restrict__ as_, const float* __restrict__ ad_,
                      const uint4* __restrict__ hp4, const float* __restrict__ bias,
                      float* __restrict__ xout){
    const int lane = threadIdx.x & 63;
    const int wid  = threadIdx.x >> 6;
    const int n    = blockIdx.x * 4 + wid;
    if (n >= N_NODES) return;
    const int beg = rowptr[n], end = rowptr[n + 1];

    const int q  = lane >> 4;       // edge slot 0..3
    const int li = lane & 15;       // row position: cols 8*li .. 8*li+7
    const int h  = li >> 1;         // head
    const float adn = ad_[(size_t)n * 8 + h];

    float acc[8];
    #pragma unroll
    for (int j = 0; j < 8; j++) acc[j] = 0.f;
    float den = 0.f;

    for (int e0 = beg; e0 < end; e0 += 4) {
        int e = e0 + q;
        bool valid = (e < end);
        int ec = valid ? e : (end - 1);
        int s = csr[ec];
        float v = as_[(size_t)s * 8 + h] + adn;
        v = v > 0.f ? v : NEG_SLOPE * v;
        float w = valid ? __expf(v) : 0.f;
        den += w;
        uint4 p = hp4[(size_t)s * 16 + li];
        acc[0] = fmaf(w, b2f((u16)(p.x & 0xffff)), acc[0]);
        acc[1] = fmaf(w, b2f((u16)(p.x >> 16)),    acc[1]);
        acc[2] = fmaf(w, b2f((u16)(p.y & 0xffff)), acc[2]);
        acc[3] = fmaf(w, b2f((u16)(p.y >> 16)),    acc[3]);
        acc[4] = fmaf(w, b2f((u16)(p.z & 0xffff)), acc[4]);
        acc[5] = fmaf(w, b2f((u16)(p.z >> 16)),    acc[5]);
        acc[6] = fmaf(w, b2f((u16)(p.w & 0xffff)), acc[6]);
        acc[7] = fmaf(w, b2f((u16)(p.w >> 16)),    acc[7]);
    }

    #pragma unroll
    for (int j = 0; j < 8; j++) {
        acc[j] += __shfl_xor(acc[j], 16);
        acc[j] += __shfl_xor(acc[j], 32);
    }
    den += __shfl_xor(den, 16);
    den += __shfl_xor(den, 32);

    if (q == 0) {
        const float inv = 1.f / (den + 1e-16f);
        const float4 b0 = *(const float4*)(bias + 8 * li);
        const float4 b1 = *(const float4*)(bias + 8 * li + 4);
        float o[8];
        o[0] = acc[0] * inv + b0.x; o[1] = acc[1] * inv + b0.y;
        o[2] = acc[2] * inv + b0.z; o[3] = acc[3] * inv + b0.w;
        o[4] = acc[4] * inv + b1.x; o[5] = acc[5] * inv + b1.y;
        o[6] = acc[6] * inv + b1.z; o[7] = acc[7] * inv + b1.w;
        #pragma unroll
        for (int j = 0; j < 8; j++)
            o[j] = o[j] > 0.f ? o[j] : (__expf(o[j]) - 1.f);   // ELU
        float* dst = xout + (size_t)n * 128 + 8 * li;
        *(float4*)(dst)     = make_float4(o[0], o[1], o[2], o[3]);
        *(float4*)(dst + 4) = make_float4(o[4], o[5], o[6], o[7]);
    }
}

// ---------------- pooling / BN / FC ----------------

#define POOL_CHUNK 50

__global__ void k_pool(const float* __restrict__ x, const int* __restrict__ batch,
                       float* __restrict__ pooled){
    int tid = threadIdx.x;             // 128 = feature
    int n0 = blockIdx.x * POOL_CHUNK;
    int nend = min(n0 + POOL_CHUNK, N_NODES);
    float acc = 0.f;
    int cur = batch[n0];
    for (int n = n0; n < nend; n++) {
        int g = batch[n];
        if (g != cur) {
            atomicAdd(&pooled[cur * 128 + tid], acc);
            acc = 0.f; cur = g;
        }
        acc += x[(size_t)n * 128 + tid];
    }
    atomicAdd(&pooled[cur * 128 + tid], acc);
}

// one wave per feature (128 waves over 32 blocks); butterfly reduce over graphs
__launch_bounds__(256)
__global__ void k_bn(const float* __restrict__ pooled, const float* __restrict__ gamma,
                     const float* __restrict__ beta, float* __restrict__ normed){
    const int lane = threadIdx.x & 63;
    const int f    = blockIdx.x * 4 + (threadIdx.x >> 6);   // feature 0..127
    const int g1 = lane, g2 = lane + 64;
    float v1 = (g1 < NGRAPH) ? pooled[g1 * 128 + f] : 0.f;
    float v2 = (g2 < NGRAPH) ? pooled[g2 * 128 + f] : 0.f;

    float s = v1 + v2;
    #pragma unroll
    for (int o = 1; o < 64; o <<= 1) s += __shfl_xor(s, o);
    const float mu = s * (1.f / NGRAPH);

    float d1 = (g1 < NGRAPH) ? (v1 - mu) : 0.f;
    float d2 = (g2 < NGRAPH) ? (v2 - mu) : 0.f;
    float q = d1 * d1 + d2 * d2;
    #pragma unroll
    for (int o = 1; o < 64; o <<= 1) q += __shfl_xor(q, o);
    const float rs = rsqrtf(q * (1.f / NGRAPH) + BN_EPS);

    const float ga = gamma[f], be = beta[f];
    if (g1 < NGRAPH) normed[g1 * 128 + f] = d1 * rs * ga + be;
    if (g2 < NGRAPH) normed[g2 * 128 + f] = d2 * rs * ga + be;
}

// one block per graph, thread per output
__launch_bounds__(64)
__global__ void k_fc(const float* __restrict__ normed, const float* __restrict__ fw,
                     const float* __restrict__ fb, float* __restrict__ out){
    const int g = blockIdx.x, j = threadIdx.x;   // 100 x 64
    float acc = fb[j];
    const float4* wr = (const float4*)(fw + j * 128);
    const float4* nr = (const float4*)(normed + g * 128);
    #pragma unroll
    for (int k = 0; k < 32; k++) {
        float4 w = wr[k], n4 = nr[k];
        acc = fmaf(n4.x, w.x, acc);
        acc = fmaf(n4.y, w.y, acc);
        acc = fmaf(n4.z, w.z, acc);
        acc = fmaf(n4.w, w.w, acc);
    }
    out[g * 64 + j] = acc;
}

// ---------------- launch ----------------

extern "C" void kernel_launch(void* const* d_in, const int* in_sizes, int n_in,
                              void* d_out, int out_size, void* d_ws, size_t ws_size,
                              hipStream_t stream) {
    const float* x0    = (const float*)d_in[0];
    const int*   ei    = (const int*)d_in[1];
    const int*   batch = (const int*)d_in[2];
    const float* Wp    = (const float*)d_in[3];
    const float* asrc  = (const float*)d_in[4];
    const float* adst  = (const float*)d_in[5];
    const float* bias  = (const float*)d_in[6];
    const float* gamma = (const float*)d_in[7];
    const float* beta  = (const float*)d_in[8];
    const float* fw    = (const float*)d_in[9];
    const float* fb    = (const float*)d_in[10];
    float* out = (float*)d_out;

    char* w = (char*)d_ws;
    size_t off = 0;
    auto take = [&](size_t bytes) -> char* {
        char* p = w + off;
        off += (bytes + 255) & ~(size_t)255;
        return p;
    };
    int*   rowptr = (int*)take((N_NODES + 1) * 4);
    int*   cur    = (int*)take((size_t)N_NODES * 4);      // also the degree histogram
    int*   bsum   = (int*)take(64 * 4);
    int*   boff   = (int*)take(64 * 4);
    int*   csr    = (int*)take((size_t)N_ETOT * 4);
    u16*   hp     = (u16*)take((size_t)N_NODES * 128 * 2);
    float* as_    = (float*)take((size_t)N_NODES * 8 * 4);
    float* ad_    = (float*)take((size_t)N_NODES * 8 * 4);
    float* xb1    = (float*)take((size_t)N_NODES * 128 * 4);
    float* xb2    = (float*)take((size_t)N_NODES * 128 * 4);
    float* pooled = (float*)take((size_t)NGRAPH * 128 * 4);
    float* normed = (float*)take((size_t)NGRAPH * 128 * 4);

    hipMemsetAsync(cur, 0, (size_t)N_NODES * 4, stream);
    hipMemsetAsync(pooled, 0, (size_t)NGRAPH * 128 * 4, stream);

    // CSR build (by destination)
    k_degree   <<<(N_ETOT + 255) / 256, 256, 0, stream>>>(ei, cur);
    k_bsum     <<<NSCAN, 256, 0, stream>>>(cur, bsum);
    k_scan_bsum<<<1, 64, 0, stream>>>(bsum, boff, rowptr);
    k_scan_local<<<NSCAN, 256, 0, stream>>>(cur, boff, rowptr);
    k_initcur  <<<(N_NODES + 255) / 256, 256, 0, stream>>>(rowptr, cur);
    k_scatter  <<<(N_ETOT + 255) / 256, 256, 0, stream>>>(ei, cur, csr);

    // 3 GAT layers
    const float* xc = x0;
    float* bufs[2] = { xb1, xb2 };
    for (int l = 0; l < 3; l++) {
        float* xn = bufs[l & 1];
        k_gemm<<<(N_NODES + 63) / 64, 256, 0, stream>>>(
            xc, Wp + (size_t)l * 128 * 128, asrc + l * 128, adst + l * 128, hp, as_, ad_);
        k_agg <<<(N_NODES + 3) / 4, 256, 0, stream>>>(
            rowptr, csr, as_, ad_, (const uint4*)hp, bias + l * 128, xn);
        xc = xn;
    }

    // pool -> BN -> FC
    k_pool<<<(N_NODES + POOL_CHUNK - 1) / POOL_CHUNK, 128, 0, stream>>>(xc, batch, pooled);
    k_bn  <<<32, 256, 0, stream>>>(pooled, gamma, beta, normed);
    k_fc  <<<NGRAPH, NLAT, 0, stream>>>(normed, fw, fb, out);
}

// Round 6
// 395.999 us; speedup vs baseline: 1.8502x; 1.1581x over previous
//
#include <hip/hip_runtime.h>
#include <cstdint>
#include <cstddef>

#define N_NODES 50000
#define N_EDGES 800000
#define N_ETOT  850000   // E + N self-loops
#define DIM     128
#define NHEAD   8
#define NGRAPH  100
#define NLAT    64
#define NEG_SLOPE 0.2f
#define BN_EPS  1e-5f

#define NBUCKET 196      // ceil(50000/256): bucket = dst>>8
#define CAP     5120     // slots per bucket (mean 4352, sigma ~64 -> +12 sigma)
#define EPB     4096     // edges per k_bin block

typedef unsigned int   u32;
typedef unsigned short u16;

__device__ __forceinline__ float b2f(u16 u){
    union { u32 i; float f; } v; v.i = ((u32)u) << 16; return v.f;
}
__device__ __forceinline__ u16 f2b(float f){
    union { float f; u32 i; } v; v.f = f;
    u32 u = v.i;
    u32 r = (u + 0x7fffu + ((u >> 16) & 1u)) >> 16;
    return (u16)r;
}

// ---------------- binned CSR build ----------------
// k_bin: stage EPB edges in LDS grouped by coarse bucket, reserve space with one
// global atomic per (block,bucket), write contiguous runs of packed records
// (src:16 | ldst:8 | bucket:8) into padded bucket regions.

__launch_bounds__(256)
__global__ void k_bin(const int* __restrict__ ei, int* __restrict__ bucket_cur,
                      u32* __restrict__ binned){
    __shared__ u32 stage[EPB];          // 16 KB
    __shared__ int hist[256], scanb[256], curb[256], gbase[256];
    const int tid = threadIdx.x;
    const int e0  = blockIdx.x * EPB;

    hist[tid] = 0;
    __syncthreads();

    // pass 1: bucket histogram
    #pragma unroll
    for (int j = 0; j < EPB / 256; j++) {
        int e = e0 + j * 256 + tid;
        if (e < N_ETOT) {
            int d = (e < N_EDGES) ? ei[N_EDGES + e] : (e - N_EDGES);
            atomicAdd(&hist[d >> 8], 1);
        }
    }
    __syncthreads();

    // exclusive scan of hist (Hillis-Steele over 256)
    __shared__ int s[256];
    s[tid] = hist[tid];
    __syncthreads();
    for (int o = 1; o < 256; o <<= 1) {
        int t = (tid >= o) ? s[tid - o] : 0;
        __syncthreads();
        s[tid] += t;
        __syncthreads();
    }
    scanb[tid] = s[tid] - hist[tid];
    curb[tid]  = 0;
    __syncthreads();

    // pass 2: stage records grouped by bucket
    #pragma unroll
    for (int j = 0; j < EPB / 256; j++) {
        int e = e0 + j * 256 + tid;
        if (e < N_ETOT) {
            int src, d;
            if (e < N_EDGES) { src = ei[e]; d = ei[N_EDGES + e]; }
            else             { src = e - N_EDGES; d = src; }
            int b = d >> 8;
            int r = atomicAdd(&curb[b], 1);
            stage[scanb[b] + r] = (u32)src | ((u32)(d & 255) << 16) | ((u32)b << 24);
        }
    }
    __syncthreads();

    // reserve global space per bucket
    if (tid < NBUCKET && hist[tid] > 0)
        gbase[tid] = atomicAdd(&bucket_cur[tid], hist[tid]);
    __syncthreads();

    // copy out: consecutive staged entries of a bucket -> consecutive global
    int nvalid = min(EPB, N_ETOT - e0);
    for (int i = tid; i < nvalid; i += 256) {
        u32 rec = stage[i];
        int b = rec >> 24;
        int pos = gbase[b] + (i - scanb[b]);
        if (pos < CAP) binned[(size_t)b * CAP + pos] = rec;
    }
}

// k_bucket: one block per bucket. Local degree histogram -> scan -> rowbeg/rowend,
// then scatter src ids into the bucket's 20KB csr window (stays in L1/L2).

__launch_bounds__(256)
__global__ void k_bucket(const int* __restrict__ bucket_cur, const u32* __restrict__ binned,
                         int* __restrict__ rowbeg, int* __restrict__ rowend,
                         int* __restrict__ csr){
    __shared__ int deg[256], off[256], cur[256], s[256];
    const int tid = threadIdx.x;
    const int b   = blockIdx.x;
    const int cnt = min(bucket_cur[b], CAP);
    const int base = b * CAP;

    deg[tid] = 0;
    __syncthreads();
    for (int i = tid; i < cnt; i += 256)
        atomicAdd(&deg[(binned[base + i] >> 16) & 255], 1);
    __syncthreads();

    s[tid] = deg[tid];
    __syncthreads();
    for (int o = 1; o < 256; o <<= 1) {
        int t = (tid >= o) ? s[tid - o] : 0;
        __syncthreads();
        s[tid] += t;
        __syncthreads();
    }
    off[tid] = s[tid] - deg[tid];
    cur[tid] = s[tid] - deg[tid];
    __syncthreads();

    int node = b * 256 + tid;
    if (node < N_NODES) {
        rowbeg[node] = base + off[tid];
        rowend[node] = base + off[tid] + deg[tid];
    }

    for (int i = tid; i < cnt; i += 256) {
        u32 rec = binned[base + i];
        int l = (rec >> 16) & 255;
        int p = atomicAdd(&cur[l], 1);
        csr[base + p] = (int)(rec & 0xffffu);
    }
}

// ---------------- per-layer: x @ W -> hp (bf16) + fused alpha logits ----------

__launch_bounds__(256)
__global__ void k_gemm(const float* __restrict__ x, const float* __restrict__ W,
                       const float* __restrict__ asrc, const float* __restrict__ adst,
                       u16* __restrict__ hp,
                       float* __restrict__ as_, float* __restrict__ ad_){
    __shared__ float xs[64 * 128];
    const int tid = threadIdx.x;
    const int r0  = blockIdx.x * 64;

    for (int c = tid; c < 2048; c += 256) {          // 64 rows x 32 float4
        int row = r0 + (c >> 5);
        float4 v = make_float4(0.f, 0.f, 0.f, 0.f);
        if (row < N_NODES) v = *(const float4*)(x + (size_t)row * 128 + (c & 31) * 4);
        *(float4*)(xs + c * 4) = v;
    }
    __syncthreads();

    const int cq = tid & 31;
    const int rg = tid >> 5;
    float acc[8][4];
    #pragma unroll
    for (int r = 0; r < 8; r++)
        #pragma unroll
        for (int c = 0; c < 4; c++) acc[r][c] = 0.f;

    for (int k = 0; k < 128; k += 4) {
        float4 w0 = *(const float4*)(W + (k + 0) * 128 + 4 * cq);
        float4 w1 = *(const float4*)(W + (k + 1) * 128 + 4 * cq);
        float4 w2 = *(const float4*)(W + (k + 2) * 128 + 4 * cq);
        float4 w3 = *(const float4*)(W + (k + 3) * 128 + 4 * cq);
        #pragma unroll
        for (int rr = 0; rr < 8; rr++) {
            float4 xv = *(const float4*)(xs + (rg * 8 + rr) * 128 + k);
            acc[rr][0] = fmaf(xv.x, w0.x, acc[rr][0]);
            acc[rr][1] = fmaf(xv.x, w0.y, acc[rr][1]);
            acc[rr][2] = fmaf(xv.x, w0.z, acc[rr][2]);
            acc[rr][3] = fmaf(xv.x, w0.w, acc[rr][3]);
            acc[rr][0] = fmaf(xv.y, w1.x, acc[rr][0]);
            acc[rr][1] = fmaf(xv.y, w1.y, acc[rr][1]);
            acc[rr][2] = fmaf(xv.y, w1.z, acc[rr][2]);
            acc[rr][3] = fmaf(xv.y, w1.w, acc[rr][3]);
            acc[rr][0] = fmaf(xv.z, w2.x, acc[rr][0]);
            acc[rr][1] = fmaf(xv.z, w2.y, acc[rr][1]);
            acc[rr][2] = fmaf(xv.z, w2.z, acc[rr][2]);
            acc[rr][3] = fmaf(xv.z, w2.w, acc[rr][3]);
            acc[rr][0] = fmaf(xv.w, w3.x, acc[rr][0]);
            acc[rr][1] = fmaf(xv.w, w3.y, acc[rr][1]);
            acc[rr][2] = fmaf(xv.w, w3.z, acc[rr][2]);
            acc[rr][3] = fmaf(xv.w, w3.w, acc[rr][3]);
        }
    }

    const int h  = cq >> 2;
    const int c0 = (cq & 3) * 4;
    const float4 av = *(const float4*)(asrc + h * 16 + c0);
    const float4 bv = *(const float4*)(adst + h * 16 + c0);

    #pragma unroll
    for (int rr = 0; rr < 8; rr++) {
        int row = r0 + rg * 8 + rr;
        if (row < N_NODES) {
            uint2 p;
            p.x = (u32)f2b(acc[rr][0]) | ((u32)f2b(acc[rr][1]) << 16);
            p.y = (u32)f2b(acc[rr][2]) | ((u32)f2b(acc[rr][3]) << 16);
            *(uint2*)(hp + (size_t)row * 128 + 4 * cq) = p;
        }
        float s0 = acc[rr][0] * av.x + acc[rr][1] * av.y + acc[rr][2] * av.z + acc[rr][3] * av.w;
        float s1 = acc[rr][0] * bv.x + acc[rr][1] * bv.y + acc[rr][2] * bv.z + acc[rr][3] * bv.w;
        s0 += __shfl_xor(s0, 1); s0 += __shfl_xor(s0, 2);
        s1 += __shfl_xor(s1, 1); s1 += __shfl_xor(s1, 2);
        if ((cq & 3) == 0 && row < N_NODES) {
            as_[(size_t)row * 8 + h] = s0;
            ad_[(size_t)row * 8 + h] = s1;
        }
    }
}

// ---------------- per-layer: single-pass segment softmax + aggregate ----------

__launch_bounds__(256)
__global__ void k_agg(const int* __restrict__ rowbeg, const int* __restrict__ rowend,
                      const int* __restrict__ csr,
                      const float* __restrict__ as_, const float* __restrict__ ad_,
                      const uint4* __restrict__ hp4, const float* __restrict__ bias,
                      float* __restrict__ xout){
    const int lane = threadIdx.x & 63;
    const int wid  = threadIdx.x >> 6;
    const int n    = blockIdx.x * 4 + wid;
    if (n >= N_NODES) return;
    const int beg = rowbeg[n], end = rowend[n];

    const int q  = lane >> 4;       // edge slot 0..3
    const int li = lane & 15;       // row position: cols 8*li .. 8*li+7
    const int h  = li >> 1;         // head
    const float adn = ad_[(size_t)n * 8 + h];

    float acc[8];
    #pragma unroll
    for (int j = 0; j < 8; j++) acc[j] = 0.f;
    float den = 0.f;

    for (int e0 = beg; e0 < end; e0 += 4) {
        int e = e0 + q;
        bool valid = (e < end);
        int ec = valid ? e : (end - 1);
        int s = csr[ec];
        float v = as_[(size_t)s * 8 + h] + adn;
        v = v > 0.f ? v : NEG_SLOPE * v;
        float w = valid ? __expf(v) : 0.f;
        den += w;
        uint4 p = hp4[(size_t)s * 16 + li];
        acc[0] = fmaf(w, b2f((u16)(p.x & 0xffff)), acc[0]);
        acc[1] = fmaf(w, b2f((u16)(p.x >> 16)),    acc[1]);
        acc[2] = fmaf(w, b2f((u16)(p.y & 0xffff)), acc[2]);
        acc[3] = fmaf(w, b2f((u16)(p.y >> 16)),    acc[3]);
        acc[4] = fmaf(w, b2f((u16)(p.z & 0xffff)), acc[4]);
        acc[5] = fmaf(w, b2f((u16)(p.z >> 16)),    acc[5]);
        acc[6] = fmaf(w, b2f((u16)(p.w & 0xffff)), acc[6]);
        acc[7] = fmaf(w, b2f((u16)(p.w >> 16)),    acc[7]);
    }

    #pragma unroll
    for (int j = 0; j < 8; j++) {
        acc[j] += __shfl_xor(acc[j], 16);
        acc[j] += __shfl_xor(acc[j], 32);
    }
    den += __shfl_xor(den, 16);
    den += __shfl_xor(den, 32);

    if (q == 0) {
        const float inv = 1.f / (den + 1e-16f);
        const float4 b0 = *(const float4*)(bias + 8 * li);
        const float4 b1 = *(const float4*)(bias + 8 * li + 4);
        float o[8];
        o[0] = acc[0] * inv + b0.x; o[1] = acc[1] * inv + b0.y;
        o[2] = acc[2] * inv + b0.z; o[3] = acc[3] * inv + b0.w;
        o[4] = acc[4] * inv + b1.x; o[5] = acc[5] * inv + b1.y;
        o[6] = acc[6] * inv + b1.z; o[7] = acc[7] * inv + b1.w;
        #pragma unroll
        for (int j = 0; j < 8; j++)
            o[j] = o[j] > 0.f ? o[j] : (__expf(o[j]) - 1.f);   // ELU
        float* dst = xout + (size_t)n * 128 + 8 * li;
        *(float4*)(dst)     = make_float4(o[0], o[1], o[2], o[3]);
        *(float4*)(dst + 4) = make_float4(o[4], o[5], o[6], o[7]);
    }
}

// ---------------- pooling / BN / FC ----------------

#define POOL_CHUNK 50

__global__ void k_pool(const float* __restrict__ x, const int* __restrict__ batch,
                       float* __restrict__ pooled){
    int tid = threadIdx.x;             // 128 = feature
    int n0 = blockIdx.x * POOL_CHUNK;
    int nend = min(n0 + POOL_CHUNK, N_NODES);
    float acc = 0.f;
    int cur = batch[n0];
    for (int n = n0; n < nend; n++) {
        int g = batch[n];
        if (g != cur) {
            atomicAdd(&pooled[cur * 128 + tid], acc);
            acc = 0.f; cur = g;
        }
        acc += x[(size_t)n * 128 + tid];
    }
    atomicAdd(&pooled[cur * 128 + tid], acc);
}

// one wave per feature (128 waves over 32 blocks); butterfly reduce over graphs
__launch_bounds__(256)
__global__ void k_bn(const float* __restrict__ pooled, const float* __restrict__ gamma,
                     const float* __restrict__ beta, float* __restrict__ normed){
    const int lane = threadIdx.x & 63;
    const int f    = blockIdx.x * 4 + (threadIdx.x >> 6);   // feature 0..127
    const int g1 = lane, g2 = lane + 64;
    float v1 = (g1 < NGRAPH) ? pooled[g1 * 128 + f] : 0.f;
    float v2 = (g2 < NGRAPH) ? pooled[g2 * 128 + f] : 0.f;

    float s = v1 + v2;
    #pragma unroll
    for (int o = 1; o < 64; o <<= 1) s += __shfl_xor(s, o);
    const float mu = s * (1.f / NGRAPH);

    float d1 = (g1 < NGRAPH) ? (v1 - mu) : 0.f;
    float d2 = (g2 < NGRAPH) ? (v2 - mu) : 0.f;
    float q = d1 * d1 + d2 * d2;
    #pragma unroll
    for (int o = 1; o < 64; o <<= 1) q += __shfl_xor(q, o);
    const float rs = rsqrtf(q * (1.f / NGRAPH) + BN_EPS);

    const float ga = gamma[f], be = beta[f];
    if (g1 < NGRAPH) normed[g1 * 128 + f] = d1 * rs * ga + be;
    if (g2 < NGRAPH) normed[g2 * 128 + f] = d2 * rs * ga + be;
}

// one block per graph, thread per output
__launch_bounds__(64)
__global__ void k_fc(const float* __restrict__ normed, const float* __restrict__ fw,
                     const float* __restrict__ fb, float* __restrict__ out){
    const int g = blockIdx.x, j = threadIdx.x;   // 100 x 64
    float acc = fb[j];
    const float4* wr = (const float4*)(fw + j * 128);
    const float4* nr = (const float4*)(normed + g * 128);
    #pragma unroll
    for (int k = 0; k < 32; k++) {
        float4 w = wr[k], n4 = nr[k];
        acc = fmaf(n4.x, w.x, acc);
        acc = fmaf(n4.y, w.y, acc);
        acc = fmaf(n4.z, w.z, acc);
        acc = fmaf(n4.w, w.w, acc);
    }
    out[g * 64 + j] = acc;
}

// ---------------- launch ----------------

extern "C" void kernel_launch(void* const* d_in, const int* in_sizes, int n_in,
                              void* d_out, int out_size, void* d_ws, size_t ws_size,
                              hipStream_t stream) {
    const float* x0    = (const float*)d_in[0];
    const int*   ei    = (const int*)d_in[1];
    const int*   batch = (const int*)d_in[2];
    const float* Wp    = (const float*)d_in[3];
    const float* asrc  = (const float*)d_in[4];
    const float* adst  = (const float*)d_in[5];
    const float* bias  = (const float*)d_in[6];
    const float* gamma = (const float*)d_in[7];
    const float* beta  = (const float*)d_in[8];
    const float* fw    = (const float*)d_in[9];
    const float* fb    = (const float*)d_in[10];
    float* out = (float*)d_out;

    char* w = (char*)d_ws;
    size_t off = 0;
    auto take = [&](size_t bytes) -> char* {
        char* p = w + off;
        off += (bytes + 255) & ~(size_t)255;
        return p;
    };
    int*   rowbeg  = (int*)take((size_t)N_NODES * 4);
    int*   rowend  = (int*)take((size_t)N_NODES * 4);
    int*   bucket_cur = (int*)take(NBUCKET * 4);
    u32*   binned  = (u32*)take((size_t)NBUCKET * CAP * 4);
    int*   csr     = (int*)take((size_t)NBUCKET * CAP * 4);
    u16*   hp      = (u16*)take((size_t)N_NODES * 128 * 2);
    float* as_     = (float*)take((size_t)N_NODES * 8 * 4);
    float* ad_     = (float*)take((size_t)N_NODES * 8 * 4);
    float* xb1     = (float*)take((size_t)N_NODES * 128 * 4);
    float* xb2     = (float*)take((size_t)N_NODES * 128 * 4);
    float* pooled  = (float*)take((size_t)NGRAPH * 128 * 4);
    float* normed  = (float*)take((size_t)NGRAPH * 128 * 4);

    hipMemsetAsync(bucket_cur, 0, NBUCKET * 4, stream);
    hipMemsetAsync(pooled, 0, (size_t)NGRAPH * 128 * 4, stream);

    // binned CSR build (by destination)
    k_bin   <<<(N_ETOT + EPB - 1) / EPB, 256, 0, stream>>>(ei, bucket_cur, binned);
    k_bucket<<<NBUCKET, 256, 0, stream>>>(bucket_cur, binned, rowbeg, rowend, csr);

    // 3 GAT layers
    const float* xc = x0;
    float* bufs[2] = { xb1, xb2 };
    for (int l = 0; l < 3; l++) {
        float* xn = bufs[l & 1];
        k_gemm<<<(N_NODES + 63) / 64, 256, 0, stream>>>(
            xc, Wp + (size_t)l * 128 * 128, asrc + l * 128, adst + l * 128, hp, as_, ad_);
        k_agg <<<(N_NODES + 3) / 4, 256, 0, stream>>>(
            rowbeg, rowend, csr, as_, ad_, (const uint4*)hp, bias + l * 128, xn);
        xc = xn;
    }

    // pool -> BN -> FC
    k_pool<<<(N_NODES + POOL_CHUNK - 1) / POOL_CHUNK, 128, 0, stream>>>(xc, batch, pooled);
    k_bn  <<<32, 256, 0, stream>>>(pooled, gamma, beta, normed);
    k_fc  <<<NGRAPH, NLAT, 0, stream>>>(normed, fw, fb, out);
}